// Round 6
// baseline (124.936 us; speedup 1.0000x reference)
//
#include <hip/hip_runtime.h>

// Pipeline: k0 W->fragment-packed Wf -> k1 QKV GEMM (pipelined 32-row panels,
// W in registers, double-buffered LDS) -> k2 attention.
// fp16 MFMA 32x32x16: A row=lane&31,k=8*(lane>>5)+i; B col=lane&31,k=8*(lane>>5)+i;
//                     C/D col=lane&31, row=(reg&3)+8*(reg>>2)+4*(lane>>5).
// fp16 MFMA 16x16x32 (attn): A row=lane&15; B col=lane&15; C/D col=lane&15,row=4*(lane>>4)+reg.

#define B_ 256
#define T_ 256
#define C_ 384
#define H_ 64

typedef __attribute__((ext_vector_type(4)))  float     f32x4;
typedef __attribute__((ext_vector_type(16))) float     f32x16;
typedef __attribute__((ext_vector_type(8)))  _Float16  f16x8;

#define MFMA16(a, b, c) __builtin_amdgcn_mfma_f32_16x16x32_f16((a), (b), (c), 0, 0, 0)
#define MFMA32(a, b, c) __builtin_amdgcn_mfma_f32_32x32x16_f16((a), (b), (c), 0, 0, 0)

// ---------------- workspace layout (bytes) ----------------
constexpr size_t WF_OFF = 0;                       // 192*384*2 = 147456 B (frag-packed)
constexpr size_t QH_OFF = 147456;                  // [65536][64] f16, pre-scaled
constexpr size_t KH_OFF = QH_OFF + 8388608;        // [65536][64] f16
constexpr size_t VT_OFF = KH_OFF + 8388608;        // [256][64][256] f16 (V^T per batch)

// ================= k0: W -> Wf (cast + fragment layout) =================
// Wf[e]: e = ((g*24+kk)*2 + hi2)*256 + l31*8 + i ; lane = l31 + 32*hi2 reads
// its f16x8 frag for col-group g (0,1=Q 2,3=K 4,5=V), k-chunk kk, contiguously.
__global__ void w_fragpack(const float* __restrict__ Wq,
                           const float* __restrict__ Wk,
                           const float* __restrict__ Wv,
                           _Float16* __restrict__ Wf) {
    int e = blockIdx.x * 256 + threadIdx.x;      // 0..73727
    int i   = e & 7;
    int l31 = (e >> 3) & 31;
    int hi2 = (e >> 8) & 1;
    int cid = e >> 9;                             // g*24 + kk
    int kk  = cid % 24;
    int g   = cid / 24;
    int col = g * 32 + l31;                       // 0..191 in [Q|K|V]
    int p   = col >> 6;
    int h   = col & 63;
    int k   = kk * 16 + hi2 * 8 + i;
    const float* W = (p == 0) ? Wq : (p == 1) ? Wk : Wv;
    Wf[e] = (_Float16)W[k * 64 + h];
}

// ================= k1: QKV = x @ [Wq|Wk|Wv], pipelined panels =================
// 512 blocks x 384 threads (6 waves: 0,1->Q 2,3->K 4,5->V). Each block: 4 panels
// of 32 rows. W frags in registers (loaded once). Double-buffered 24KB LDS,
// prefetch panel i+1 into regs during compute of panel i (T14/T3-min).
__global__ __launch_bounds__(384, 3) void qkv_gemm(
    const float* __restrict__ x, const _Float16* __restrict__ Wf,
    _Float16* __restrict__ Qh, _Float16* __restrict__ Kh,
    _Float16* __restrict__ Vt)
{
    __shared__ _Float16 xs[2][32 * 384];         // 2 x 24KB, swizzled g^(row&15)

    const int tid = threadIdx.x, lane = tid & 63, w = tid >> 6;
    const int l31 = lane & 31, hi2 = lane >> 5;
    const int blk = blockIdx.x;
    const bool isV = (w >= 4);
    const float scale = (w < 2) ? 0.125f : 1.0f;

    // ---- W fragments, once ----
    f16x8 wreg[24];
    {
        const _Float16* wbase = Wf + (size_t)(w * 24) * 512 + lane * 8;
        #pragma unroll
        for (int j = 0; j < 24; ++j)
            wreg[j] = *(const f16x8*)(wbase + j * 512);
    }

    // ---- stage panel 0 ----
    {
        const float* xp = x + (size_t)(blk * 4) * 32 * C_;
        #pragma unroll
        for (int i = 0; i < 4; ++i) {
            int chunk = tid + i * 384;           // 0..1535 : 8-f32 chunks
            int row = chunk / 48, c8 = chunk - row * 48;
            const float* gp = xp + row * C_ + c8 * 8;
            float4 u = *(const float4*)gp;
            float4 v = *(const float4*)(gp + 4);
            f16x8 hv = {(_Float16)u.x, (_Float16)u.y, (_Float16)u.z, (_Float16)u.w,
                        (_Float16)v.x, (_Float16)v.y, (_Float16)v.z, (_Float16)v.w};
            int g = c8 ^ (row & 15);
            *(f16x8*)(&xs[0][row * 384 + g * 8]) = hv;
        }
    }
    __syncthreads();

    #pragma unroll
    for (int it = 0; it < 4; ++it) {
        const int cur = it & 1;

        // ---- issue prefetch loads for panel it+1 (regs; latency hides under MFMA) ----
        float4 pu[4], pv[4];
        if (it < 3) {
            const float* xp = x + (size_t)(blk * 4 + it + 1) * 32 * C_;
            #pragma unroll
            for (int i = 0; i < 4; ++i) {
                int chunk = tid + i * 384;
                int row = chunk / 48, c8 = chunk - row * 48;
                const float* gp = xp + row * C_ + c8 * 8;
                pu[i] = *(const float4*)gp;
                pv[i] = *(const float4*)(gp + 4);
            }
        }

        // ---- compute panel it: 24 x (ds_read_b128 + MFMA) ----
        f32x16 acc = {};
        const int s15 = l31 & 15;
        #pragma unroll
        for (int kk = 0; kk < 24; ++kk) {
            f16x8 xf = *(const f16x8*)(&xs[cur][l31 * 384 + ((kk * 2 + hi2) ^ s15) * 8]);
            if (!isV) acc = MFMA32(xf, wreg[kk], acc);       // D[t][n]
            else      acc = MFMA32(wreg[kk], xf, acc);       // D[h][t]
        }
        __syncthreads();                          // all waves done reading xs[cur]

        // ---- write prefetched panel into other buffer ----
        if (it < 3) {
            #pragma unroll
            for (int i = 0; i < 4; ++i) {
                int chunk = tid + i * 384;
                int row = chunk / 48, c8 = chunk - row * 48;
                f16x8 hv = {(_Float16)pu[i].x, (_Float16)pu[i].y, (_Float16)pu[i].z, (_Float16)pu[i].w,
                            (_Float16)pv[i].x, (_Float16)pv[i].y, (_Float16)pv[i].z, (_Float16)pv[i].w};
                int g = c8 ^ (row & 15);
                *(f16x8*)(&xs[cur ^ 1][row * 384 + g * 8]) = hv;
            }
        }

        // ---- repack acc into xs[cur] (freed by the barrier) ----
        // regions (halfs): Q [32t][64n] @0, K @2048, V [64h][32t] @4096
        #pragma unroll
        for (int reg = 0; reg < 16; ++reg) {
            int rr = (reg & 3) + 8 * (reg >> 2) + 4 * hi2;   // 0..31
            if (!isV) {
                int region = (w < 2) ? 0 : 2048;
                xs[cur][region + rr * 64 + (w & 1) * 32 + l31] = (_Float16)(scale * acc[reg]);
            } else {
                int h = (w - 4) * 32 + rr;
                xs[cur][4096 + h * 32 + l31] = (_Float16)acc[reg];
            }
        }
        __syncthreads();

        // ---- coalesced stores from xs[cur] ----
        const int pg = blk * 4 + it;              // global panel id
        #pragma unroll
        for (int i = 0; i < 2; ++i) {
            int c = tid + i * 384;                // 0..767 : 16B chunks
            f16x8 vv = *(const f16x8*)(&xs[cur][c * 8]);
            if (c < 256) {
                int tl = c >> 3, n8 = c & 7;
                *(f16x8*)(Qh + (size_t)(pg * 32 + tl) * 64 + n8 * 8) = vv;
            } else if (c < 512) {
                int c2 = c - 256, tl = c2 >> 3, n8 = c2 & 7;
                *(f16x8*)(Kh + (size_t)(pg * 32 + tl) * 64 + n8 * 8) = vv;
            } else {
                int c3 = c - 512, h = c3 >> 2, t8 = (c3 & 3) * 8;
                *(f16x8*)(Vt + (size_t)(pg >> 3) * 16384 + (size_t)h * 256
                          + (pg & 7) * 32 + t8) = vv;
            }
        }
    }
}

// ================= k2: attention per batch =================
// 256 blocks x 512 threads (8 indep waves, 32 q-rows each). LDS only for P-bounce.
constexpr int SP = 72;

__global__ __launch_bounds__(512, 2) void attn(
    const _Float16* __restrict__ Qh, const _Float16* __restrict__ Kh,
    const _Float16* __restrict__ Vt, float* __restrict__ out)
{
    __shared__ _Float16 Ps[8 * 32 * SP];
    const int tid = threadIdx.x, lane = tid & 63, wid = tid >> 6;
    const int lo = lane & 15, hi = lane >> 4;
    const int b = blockIdx.x;
    const int ctmax = 2 * wid + 1;               // last S column-tile with valid entries

    f16x8 aq[2][2];
    #pragma unroll
    for (int rt = 0; rt < 2; ++rt)
        #pragma unroll
        for (int ks = 0; ks < 2; ++ks)
            aq[rt][ks] = *(const f16x8*)(Qh + (size_t)(b * 256 + 32 * wid + 16 * rt + lo) * 64
                                         + 32 * ks + 8 * hi);

    f32x4 sacc[2][16] = {};
    #pragma unroll
    for (int ct = 0; ct < 16; ++ct) {
        if (ct <= ctmax) {
            #pragma unroll
            for (int ks = 0; ks < 2; ++ks) {
                f16x8 bk = *(const f16x8*)(Kh + (size_t)(b * 256 + 16 * ct + lo) * 64
                                           + 32 * ks + 8 * hi);
                sacc[0][ct] = MFMA16(aq[0][ks], bk, sacc[0][ct]);
                sacc[1][ct] = MFMA16(aq[1][ks], bk, sacc[1][ct]);
            }
        }
    }

    #pragma unroll
    for (int rt = 0; rt < 2; ++rt) {
        #pragma unroll
        for (int reg = 0; reg < 4; ++reg) {
            const int rowg = 32 * wid + 16 * rt + 4 * hi + reg;
            float m = -1e30f;
            #pragma unroll
            for (int ct = 0; ct < 16; ++ct) if (ct <= ctmax) {
                float v = sacc[rt][ct][reg];
                v = (16 * ct + lo <= rowg) ? v : -1e30f;
                sacc[rt][ct][reg] = v;
                m = fmaxf(m, v);
            }
            #pragma unroll
            for (int s = 1; s < 16; s <<= 1) m = fmaxf(m, __shfl_xor(m, s, 16));
            float l = 0.f;
            #pragma unroll
            for (int ct = 0; ct < 16; ++ct) if (ct <= ctmax) {
                float v = sacc[rt][ct][reg];
                float p = (v > -1e29f) ? __expf(v - m) : 0.f;
                sacc[rt][ct][reg] = p;
                l += p;
            }
            #pragma unroll
            for (int s = 1; s < 16; s <<= 1) l += __shfl_xor(l, s, 16);
            float rinv = 1.f / l;
            #pragma unroll
            for (int ct = 0; ct < 16; ++ct) if (ct <= ctmax) sacc[rt][ct][reg] *= rinv;
        }
    }

    f32x4 oacc[2][4] = {};
    _Float16* Pw = Ps + wid * 32 * SP;
    const int kcmax = ctmax >> 2;
    #pragma unroll
    for (int kc = 0; kc < 4; ++kc) {
        if (kc <= kcmax) {
            #pragma unroll
            for (int rt = 0; rt < 2; ++rt)
                #pragma unroll
                for (int c = 0; c < 4; ++c) {
                    const int ct = 4 * kc + c;
                    #pragma unroll
                    for (int reg = 0; reg < 4; ++reg) {
                        float v = (ct <= ctmax) ? sacc[rt][ct][reg] : 0.f;
                        Pw[(16 * rt + 4 * hi + reg) * SP + c * 16 + lo] = (_Float16)v;
                    }
                }
            asm volatile("s_waitcnt lgkmcnt(0)" ::: "memory");
            #pragma unroll
            for (int ks = 0; ks < 2; ++ks) {
                f16x8 a0 = *(const f16x8*)(Pw + lo * SP + 32 * ks + 8 * hi);
                f16x8 a1 = *(const f16x8*)(Pw + (16 + lo) * SP + 32 * ks + 8 * hi);
                #pragma unroll
                for (int ht = 0; ht < 4; ++ht) {
                    f16x8 bv = *(const f16x8*)(Vt + (size_t)b * 16384 + (size_t)(16 * ht + lo) * 256
                                               + 64 * kc + 32 * ks + 8 * hi);
                    oacc[0][ht] = MFMA16(a0, bv, oacc[0][ht]);
                    oacc[1][ht] = MFMA16(a1, bv, oacc[1][ht]);
                }
            }
            asm volatile("s_waitcnt lgkmcnt(0)" ::: "memory");
        }
    }

    float* ob = out + (size_t)b * (T_ * H_);
    #pragma unroll
    for (int rt = 0; rt < 2; ++rt)
        #pragma unroll
        for (int ht = 0; ht < 4; ++ht)
            #pragma unroll
            for (int reg = 0; reg < 4; ++reg) {
                const int t = 32 * wid + 16 * rt + 4 * hi + reg;
                ob[t * H_ + 16 * ht + lo] = oacc[rt][ht][reg];
            }
}

extern "C" void kernel_launch(void* const* d_in, const int* in_sizes, int n_in,
                              void* d_out, int out_size, void* d_ws, size_t ws_size,
                              hipStream_t stream) {
    const float* x  = (const float*)d_in[0];
    const float* Wq = (const float*)d_in[1];
    const float* Wk = (const float*)d_in[2];
    const float* Wv = (const float*)d_in[3];
    float* out = (float*)d_out;
    (void)in_sizes; (void)n_in; (void)out_size; (void)ws_size;

    char* ws = (char*)d_ws;
    _Float16* Wf = (_Float16*)(ws + WF_OFF);
    _Float16* Qh = (_Float16*)(ws + QH_OFF);
    _Float16* Kh = (_Float16*)(ws + KH_OFF);
    _Float16* Vt = (_Float16*)(ws + VT_OFF);

    w_fragpack<<<dim3(288), dim3(256), 0, stream>>>(Wq, Wk, Wv, Wf);
    qkv_gemm<<<dim3(512), dim3(384), 0, stream>>>(x, Wf, Qh, Kh, Vt);
    attn<<<dim3(B_), dim3(512), 0, stream>>>(Qh, Kh, Vt, out);
}

// Round 7
// 57.138 us; speedup vs baseline: 2.1866x; 2.1866x over previous
//
#include <hip/hip_runtime.h>

// Pipeline: k0 W->fragment-packed Wf -> k1 QKV GEMM (32-row tiles, high block
// residency, W streamed from L2 via rolling buffer) -> k2 attention.
// fp16 MFMA 32x32x16: A row=lane&31,k=8*(lane>>5)+i; B col=lane&31,k=8*(lane>>5)+i;
//                     C/D col=lane&31, row=(reg&3)+8*(reg>>2)+4*(lane>>5).
// fp16 MFMA 16x16x32 (attn): A row=lane&15; B col=lane&15; C/D col=lane&15,row=4*(lane>>4)+reg.

#define B_ 256
#define T_ 256
#define C_ 384
#define H_ 64

typedef __attribute__((ext_vector_type(4)))  float     f32x4;
typedef __attribute__((ext_vector_type(16))) float     f32x16;
typedef __attribute__((ext_vector_type(8)))  _Float16  f16x8;

#define MFMA16(a, b, c) __builtin_amdgcn_mfma_f32_16x16x32_f16((a), (b), (c), 0, 0, 0)
#define MFMA32(a, b, c) __builtin_amdgcn_mfma_f32_32x32x16_f16((a), (b), (c), 0, 0, 0)

// ---------------- workspace layout (bytes) ----------------
constexpr size_t WF_OFF = 0;                       // 192*384*2 = 147456 B (frag-packed)
constexpr size_t QH_OFF = 147456;                  // [65536][64] f16, pre-scaled
constexpr size_t KH_OFF = QH_OFF + 8388608;        // [65536][64] f16
constexpr size_t VT_OFF = KH_OFF + 8388608;        // [256][64][256] f16 (V^T per batch)

// ================= k0: W -> Wf (cast + fragment layout) =================
// Wf[e]: e = ((g*24+kk)*2 + hi2)*256 + l31*8 + i ; lane = l31 + 32*hi2 reads
// its f16x8 frag for col-group g (0,1=Q 2,3=K 4,5=V), k-chunk kk, contiguously.
__global__ void w_fragpack(const float* __restrict__ Wq,
                           const float* __restrict__ Wk,
                           const float* __restrict__ Wv,
                           _Float16* __restrict__ Wf) {
    int e = blockIdx.x * 256 + threadIdx.x;      // 0..73727
    int i   = e & 7;
    int l31 = (e >> 3) & 31;
    int hi2 = (e >> 8) & 1;
    int cid = e >> 9;                             // g*24 + kk
    int kk  = cid % 24;
    int g   = cid / 24;
    int col = g * 32 + l31;                       // 0..191 in [Q|K|V]
    int p   = col >> 6;
    int h   = col & 63;
    int k   = kk * 16 + hi2 * 8 + i;
    const float* W = (p == 0) ? Wq : (p == 1) ? Wk : Wv;
    Wf[e] = (_Float16)W[k * 64 + h];
}

// ================= k1: QKV = x @ [Wq|Wk|Wv], 32-row tiles =================
// 2048 blocks x 384 threads (6 waves: w0,1->Q cols, w2,3->K, w4,5->V rows).
// 24KB LDS tile -> high block residency; W streamed from L2 (rolling 4-deep).
__global__ __launch_bounds__(384, 4) void qkv_gemm(
    const float* __restrict__ x, const _Float16* __restrict__ Wf,
    _Float16* __restrict__ Qh, _Float16* __restrict__ Kh,
    _Float16* __restrict__ Vt)
{
    __shared__ _Float16 xs[32 * 384];            // swizzled: 16B-group g = c8 ^ (row&15)

    const int tid = threadIdx.x, lane = tid & 63, w = tid >> 6;
    const int l31 = lane & 31, hi2 = lane >> 5;
    const int pg  = blockIdx.x;                   // panel id: rows pg*32..+31
    const float* xb = x + (size_t)pg * 32 * C_;
    const bool isV = (w >= 4);
    const float scale = (w < 2) ? 0.125f : 1.0f;

    // ---- stage x[32][384] fp32 -> fp16 LDS, coalesced ----
    #pragma unroll
    for (int i = 0; i < 4; ++i) {
        int chunk = tid + i * 384;               // 0..1535 : 8-f32 chunks
        int row = chunk / 48, c8 = chunk - row * 48;
        const float* gp = xb + row * C_ + c8 * 8;
        float4 u = *(const float4*)gp;
        float4 v = *(const float4*)(gp + 4);
        f16x8 hv = {(_Float16)u.x, (_Float16)u.y, (_Float16)u.z, (_Float16)u.w,
                    (_Float16)v.x, (_Float16)v.y, (_Float16)v.z, (_Float16)v.w};
        int g = c8 ^ (row & 15);
        *(f16x8*)(xs + row * 384 + g * 8) = hv;
    }
    __syncthreads();

    // ---- compute: rolling 4-deep W stream + ds_read + MFMA ----
    const _Float16* wbase = Wf + (size_t)(w * 24) * 512 + lane * 8;
    const int s15 = l31 & 15;

    f16x8 wbuf[4];
    #pragma unroll
    for (int j = 0; j < 4; ++j)
        wbuf[j] = *(const f16x8*)(wbase + j * 512);

    f32x16 acc = {};
    #pragma unroll
    for (int kk = 0; kk < 24; ++kk) {
        f16x8 wf = wbuf[kk & 3];
        if (kk + 4 < 24)
            wbuf[kk & 3] = *(const f16x8*)(wbase + (kk + 4) * 512);
        f16x8 xf = *(const f16x8*)(xs + l31 * 384 + ((kk * 2 + hi2) ^ s15) * 8);
        if (!isV) acc = MFMA32(xf, wf, acc);      // D[t][n]
        else      acc = MFMA32(wf, xf, acc);      // D[h][t]
    }
    __syncthreads();                              // everyone done reading xs

    // ---- repack acc into xs for full-line stores ----
    // regions (halfs): Q [32t][64n] @0, K @2048, V [64h][32t] @4096
    #pragma unroll
    for (int reg = 0; reg < 16; ++reg) {
        int rr = (reg & 3) + 8 * (reg >> 2) + 4 * hi2;   // 0..31
        if (!isV) {
            int region = (w < 2) ? 0 : 2048;
            xs[region + rr * 64 + (w & 1) * 32 + l31] = (_Float16)(scale * acc[reg]);
        } else {
            int h = (w - 4) * 32 + rr;
            xs[4096 + h * 32 + l31] = (_Float16)acc[reg];
        }
    }
    __syncthreads();

    // ---- coalesced stores ----
    const int b = pg >> 3, tbase = (pg & 7) * 32;
    #pragma unroll
    for (int i = 0; i < 2; ++i) {
        int c = tid + i * 384;                    // 0..767 : 16B chunks
        f16x8 vv = *(const f16x8*)(xs + c * 8);
        if (c < 256) {
            int tl = c >> 3, n8 = c & 7;
            *(f16x8*)(Qh + (size_t)(pg * 32 + tl) * 64 + n8 * 8) = vv;
        } else if (c < 512) {
            int c2 = c - 256, tl = c2 >> 3, n8 = c2 & 7;
            *(f16x8*)(Kh + (size_t)(pg * 32 + tl) * 64 + n8 * 8) = vv;
        } else {
            int c3 = c - 512, h = c3 >> 2, t8 = (c3 & 3) * 8;
            *(f16x8*)(Vt + (size_t)b * 16384 + (size_t)h * 256 + tbase + t8) = vv;
        }
    }
}

// ================= k2: attention per batch =================
// 256 blocks x 512 threads (8 indep waves, 32 q-rows each). LDS only for P-bounce.
constexpr int SP = 72;

__global__ __launch_bounds__(512, 2) void attn(
    const _Float16* __restrict__ Qh, const _Float16* __restrict__ Kh,
    const _Float16* __restrict__ Vt, float* __restrict__ out)
{
    __shared__ _Float16 Ps[8 * 32 * SP];
    const int tid = threadIdx.x, lane = tid & 63, wid = tid >> 6;
    const int lo = lane & 15, hi = lane >> 4;
    const int b = blockIdx.x;
    const int ctmax = 2 * wid + 1;               // last S column-tile with valid entries

    f16x8 aq[2][2];
    #pragma unroll
    for (int rt = 0; rt < 2; ++rt)
        #pragma unroll
        for (int ks = 0; ks < 2; ++ks)
            aq[rt][ks] = *(const f16x8*)(Qh + (size_t)(b * 256 + 32 * wid + 16 * rt + lo) * 64
                                         + 32 * ks + 8 * hi);

    f32x4 sacc[2][16] = {};
    #pragma unroll
    for (int ct = 0; ct < 16; ++ct) {
        if (ct <= ctmax) {
            #pragma unroll
            for (int ks = 0; ks < 2; ++ks) {
                f16x8 bk = *(const f16x8*)(Kh + (size_t)(b * 256 + 16 * ct + lo) * 64
                                           + 32 * ks + 8 * hi);
                sacc[0][ct] = MFMA16(aq[0][ks], bk, sacc[0][ct]);
                sacc[1][ct] = MFMA16(aq[1][ks], bk, sacc[1][ct]);
            }
        }
    }

    #pragma unroll
    for (int rt = 0; rt < 2; ++rt) {
        #pragma unroll
        for (int reg = 0; reg < 4; ++reg) {
            const int rowg = 32 * wid + 16 * rt + 4 * hi + reg;
            float m = -1e30f;
            #pragma unroll
            for (int ct = 0; ct < 16; ++ct) if (ct <= ctmax) {
                float v = sacc[rt][ct][reg];
                v = (16 * ct + lo <= rowg) ? v : -1e30f;
                sacc[rt][ct][reg] = v;
                m = fmaxf(m, v);
            }
            #pragma unroll
            for (int s = 1; s < 16; s <<= 1) m = fmaxf(m, __shfl_xor(m, s, 16));
            float l = 0.f;
            #pragma unroll
            for (int ct = 0; ct < 16; ++ct) if (ct <= ctmax) {
                float v = sacc[rt][ct][reg];
                float p = (v > -1e29f) ? __expf(v - m) : 0.f;
                sacc[rt][ct][reg] = p;
                l += p;
            }
            #pragma unroll
            for (int s = 1; s < 16; s <<= 1) l += __shfl_xor(l, s, 16);
            float rinv = 1.f / l;
            #pragma unroll
            for (int ct = 0; ct < 16; ++ct) if (ct <= ctmax) sacc[rt][ct][reg] *= rinv;
        }
    }

    f32x4 oacc[2][4] = {};
    _Float16* Pw = Ps + wid * 32 * SP;
    const int kcmax = ctmax >> 2;
    #pragma unroll
    for (int kc = 0; kc < 4; ++kc) {
        if (kc <= kcmax) {
            #pragma unroll
            for (int rt = 0; rt < 2; ++rt)
                #pragma unroll
                for (int c = 0; c < 4; ++c) {
                    const int ct = 4 * kc + c;
                    #pragma unroll
                    for (int reg = 0; reg < 4; ++reg) {
                        float v = (ct <= ctmax) ? sacc[rt][ct][reg] : 0.f;
                        Pw[(16 * rt + 4 * hi + reg) * SP + c * 16 + lo] = (_Float16)v;
                    }
                }
            asm volatile("s_waitcnt lgkmcnt(0)" ::: "memory");
            #pragma unroll
            for (int ks = 0; ks < 2; ++ks) {
                f16x8 a0 = *(const f16x8*)(Pw + lo * SP + 32 * ks + 8 * hi);
                f16x8 a1 = *(const f16x8*)(Pw + (16 + lo) * SP + 32 * ks + 8 * hi);
                #pragma unroll
                for (int ht = 0; ht < 4; ++ht) {
                    f16x8 bv = *(const f16x8*)(Vt + (size_t)b * 16384 + (size_t)(16 * ht + lo) * 256
                                               + 64 * kc + 32 * ks + 8 * hi);
                    oacc[0][ht] = MFMA16(a0, bv, oacc[0][ht]);
                    oacc[1][ht] = MFMA16(a1, bv, oacc[1][ht]);
                }
            }
            asm volatile("s_waitcnt lgkmcnt(0)" ::: "memory");
        }
    }

    float* ob = out + (size_t)b * (T_ * H_);
    #pragma unroll
    for (int rt = 0; rt < 2; ++rt)
        #pragma unroll
        for (int ht = 0; ht < 4; ++ht)
            #pragma unroll
            for (int reg = 0; reg < 4; ++reg) {
                const int t = 32 * wid + 16 * rt + 4 * hi + reg;
                ob[t * H_ + 16 * ht + lo] = oacc[rt][ht][reg];
            }
}

extern "C" void kernel_launch(void* const* d_in, const int* in_sizes, int n_in,
                              void* d_out, int out_size, void* d_ws, size_t ws_size,
                              hipStream_t stream) {
    const float* x  = (const float*)d_in[0];
    const float* Wq = (const float*)d_in[1];
    const float* Wk = (const float*)d_in[2];
    const float* Wv = (const float*)d_in[3];
    float* out = (float*)d_out;
    (void)in_sizes; (void)n_in; (void)out_size; (void)ws_size;

    char* ws = (char*)d_ws;
    _Float16* Wf = (_Float16*)(ws + WF_OFF);
    _Float16* Qh = (_Float16*)(ws + QH_OFF);
    _Float16* Kh = (_Float16*)(ws + KH_OFF);
    _Float16* Vt = (_Float16*)(ws + VT_OFF);

    w_fragpack<<<dim3(288), dim3(256), 0, stream>>>(Wq, Wk, Wv, Wf);
    qkv_gemm<<<dim3(2048), dim3(384), 0, stream>>>(x, Wf, Qh, Kh, Vt);
    attn<<<dim3(B_), dim3(512), 0, stream>>>(Qh, Kh, Vt, out);
}